// Round 20
// baseline (446.386 us; speedup 1.0000x reference)
//
#include <hip/hip_runtime.h>
#include <hip/hip_bf16.h>
#include <cstdint>

#define D_DIM 1024
#define H_DIM 4096
#define E_NUM 8
#define NTOK  8192

#define BM 128
#define BN 128
#define BK 32

#define MAXT 72             // worst-case 128-row tiles: sum ceil(ne/128) <= 71
#define NBY1 (H_DIM / BN)   // 32
#define NBY2 (D_DIM / BN)   // 8

// fused_aux grid: [0,512) W1 slabs | [512,2560) W2 slabs | [2560,4608) gate
#define NW1B 512
#define NW2B 2048
#define NAUX (NW1B + NW2B + 2048)

typedef __bf16 bf16;
typedef __bf16 bf16x8 __attribute__((ext_vector_type(8)));
typedef __bf16 bf16x4 __attribute__((ext_vector_type(4)));
typedef float  f32x4  __attribute__((ext_vector_type(4)));

// global_load_lds: per-lane global src, wave-uniform LDS base + lane*16B dest
#define GLOAD16(g, l)                                                          \
    __builtin_amdgcn_global_load_lds(                                          \
        (const __attribute__((address_space(1))) void*)(g),                    \
        (__attribute__((address_space(3))) void*)(l), 16, 0, 0)

// zero cnt + cpartial
__global__ __launch_bounds__(256) void zero_kernel(int* cnt, float* cpartial)
{
    const int i = blockIdx.x * 256 + threadIdx.x;
    if (i < E_NUM * D_DIM) cpartial[i] = 0.f;
    if (i < E_NUM) cnt[i] = 0;
}

// ---------------- fused aux: slab transposes (sequential fp32 reads) | gate ----------------
// W2 slab: 16 consecutive h-rows (64KB fully sequential read) -> 16 blocked
// W2t tiles (+cpart from the same register values). W1 slab: 16 d-rows,
// processed as 4 chunks of [16][1024] (4KB-granule reads). Blocked-tile
// writes identical byte layout to R19 (GEMM readers unchanged).
__global__ __launch_bounds__(256) void fused_aux_kernel(
    const float* __restrict__ W2, const float* __restrict__ W1,
    const float* __restrict__ b1,
    const float* __restrict__ x, const float* __restrict__ Wg,
    const float* __restrict__ bg,
    bf16* __restrict__ W2t, bf16* __restrict__ W1t,
    float* __restrict__ cpartial,
    float* __restrict__ out_probs, float* __restrict__ out_idx,
    int* __restrict__ cnt, int* __restrict__ list)
{
    __shared__ bf16 T[16][1032];   // padded: column reads ~2-way max
    const int b = blockIdx.x;
    const int t = threadIdx.x;

    if (b < NW1B) {
        // W1 slab: e, 16 d-rows d0..d0+15, all H cols in 4 chunks of 1024
        const int e = b >> 6, slab = b & 63;
        const int d0 = slab * 16;
        const float* src = W1 + (size_t)e * D_DIM * H_DIM + (size_t)d0 * H_DIM;
        const int kx = d0 >> 6, kk = d0 & 63;
        for (int hc = 0; hc < 4; hc++) {
            // read chunk [16][1024]: 16 segments of 4KB (stride 16KB)
#pragma unroll
            for (int c = 0; c < 16; c++) {
                const int f = c * 256 + t;
                const int row = f >> 8, col4 = (f & 255) * 4;
                f32x4 v = __builtin_nontemporal_load(
                    (const f32x4*)(src + (size_t)row * H_DIM + hc * 1024 + col4));
                bf16x4 o; o[0] = (bf16)v[0]; o[1] = (bf16)v[1];
                o[2] = (bf16)v[2]; o[3] = (bf16)v[3];
                *(bf16x4*)&T[row][col4] = o;
            }
            __syncthreads();
            // write 16 blocked tiles (ny = hc*16+ti), 32B per (tile,row)
#pragma unroll
            for (int w = 0; w < 4; w++) {
                const int p = w * 256 + t;
                const int ti = p >> 6, n = p & 63;
                const int ny = hc * 16 + ti;
                bf16* dtile = W1t + (size_t)e * D_DIM * H_DIM
                            + ((size_t)ny * (D_DIM / 64) + kx) * 4096;
                bf16 tmp[16];
#pragma unroll
                for (int j = 0; j < 16; j++) tmp[j] = T[j][ti * 64 + n];
                *(bf16x8*)(dtile + n * 64 + kk)     = *(bf16x8*)&tmp[0];
                *(bf16x8*)(dtile + n * 64 + kk + 8) = *(bf16x8*)&tmp[8];
            }
            __syncthreads();
        }
    } else if (b < NW1B + NW2B) {
        // W2 slab: e, 16 consecutive h-rows (fully sequential 64KB read)
        const int b2 = b - NW1B;
        const int e = b2 >> 8, slab = b2 & 255;
        const int k0 = slab * 16;
        const float* src = W2 + (size_t)e * H_DIM * D_DIM + (size_t)k0 * D_DIM;
        const int kx = k0 >> 6, kk = k0 & 63;
        float rb1[16];
#pragma unroll
        for (int j = 0; j < 16; j++)
            rb1[j] = fmaxf(b1[(size_t)e * H_DIM + k0 + j], 0.f);
#pragma unroll
        for (int c = 0; c < 16; c++) {
            const int f = c * 256 + t;       // flat float4 index: sequential
            const int row = f >> 8, col4 = (f & 255) * 4;
            f32x4 v = __builtin_nontemporal_load(
                (const f32x4*)(src + (size_t)row * D_DIM + col4));
            bf16x4 o; o[0] = (bf16)v[0]; o[1] = (bf16)v[1];
            o[2] = (bf16)v[2]; o[3] = (bf16)v[3];
            *(bf16x4*)&T[row][col4] = o;
        }
        __syncthreads();
#pragma unroll
        for (int w = 0; w < 4; w++) {
            const int p = w * 256 + t;
            const int ti = p >> 6, n = p & 63;   // d-tile, row within tile
            bf16* dtile = W2t + (size_t)e * H_DIM * D_DIM
                        + ((size_t)ti * (H_DIM / 64) + kx) * 4096;
            bf16 tmp[16];
#pragma unroll
            for (int j = 0; j < 16; j++) tmp[j] = T[j][ti * 64 + n];
            *(bf16x8*)(dtile + n * 64 + kk)     = *(bf16x8*)&tmp[0];
            *(bf16x8*)(dtile + n * 64 + kk + 8) = *(bf16x8*)&tmp[8];
            // cpart from the same values (no extra LDS traffic)
            float s = 0.f;
#pragma unroll
            for (int j = 0; j < 16; j++) s += rb1[j] * (float)tmp[j];
            atomicAdd(&cpartial[(size_t)e * D_DIM + ti * 64 + n], s);
        }
    } else {
        // gating: 4 tokens/block, one wave each
        const int tok = (b - NW1B - NW2B) * 4 + (t >> 6);
        const int l = t & 63;
        double part[E_NUM];
#pragma unroll
        for (int e = 0; e < E_NUM; e++) part[e] = 0.0;
        const float* xr = x + (size_t)tok * D_DIM;
#pragma unroll
        for (int i = 0; i < D_DIM / 64; i++) {
            const int d = l + i * 64;
            const float xv = xr[d];
            const float* wr = Wg + (size_t)d * E_NUM;
            float4 w0 = *(const float4*)(wr);
            float4 w1 = *(const float4*)(wr + 4);
            part[0] += (double)xv * (double)w0.x;
            part[1] += (double)xv * (double)w0.y;
            part[2] += (double)xv * (double)w0.z;
            part[3] += (double)xv * (double)w0.w;
            part[4] += (double)xv * (double)w1.x;
            part[5] += (double)xv * (double)w1.y;
            part[6] += (double)xv * (double)w1.z;
            part[7] += (double)xv * (double)w1.w;
        }
#pragma unroll
        for (int e = 0; e < E_NUM; e++) {
            double v = part[e];
            for (int s = 32; s > 0; s >>= 1) v += __shfl_xor(v, s, 64);
            part[e] = v;
        }
        if (l == 0) {
            float logits[E_NUM], probs[E_NUM];
            float m = -3.0e38f;
#pragma unroll
            for (int e = 0; e < E_NUM; e++) {
                logits[e] = (float)(part[e] + (double)bg[e]);
                m = fmaxf(m, logits[e]);
            }
            float s = 0.f;
#pragma unroll
            for (int e = 0; e < E_NUM; e++) { probs[e] = expf(logits[e] - m); s += probs[e]; }
            const float inv = 1.f / s;
            int best = 0; float bp = -1.f;
#pragma unroll
            for (int e = 0; e < E_NUM; e++) {
                probs[e] *= inv;
                if (probs[e] > bp) { bp = probs[e]; best = e; }
            }
#pragma unroll
            for (int e = 0; e < E_NUM; e++) out_probs[(size_t)tok * E_NUM + e] = probs[e];
            out_idx[tok] = (float)best;
            const int pos = atomicAdd(&cnt[best], 1);
            list[best * NTOK + pos] = tok;
        }
    }
}

// prefix offsets + compact row-tile table (expert, local row0 of each 128-row tile)
__global__ void offsets_kernel(const int* __restrict__ cnt, int* __restrict__ off,
                               int* __restrict__ tile_e, int* __restrict__ tile_row,
                               int* __restrict__ tile_n)
{
    if (threadIdx.x == 0) {
        int a = 0, n = 0;
        for (int e = 0; e < E_NUM; e++) {
            off[e] = a; a += cnt[e];
            for (int rr = 0; rr < cnt[e]; rr += BM) {
                tile_e[n] = e; tile_row[n] = rr; n++;
            }
        }
        tile_n[0] = n;
    }
}

// gather routed x rows into bf16, contiguous per expert.
// Blocks >= NTOK run cfinal (adj from cpartial) — independent work fused.
__global__ __launch_bounds__(256) void gather_kernel(
    const float* __restrict__ x, const int* __restrict__ off,
    const int* __restrict__ cnt, const int* __restrict__ list,
    bf16* __restrict__ Xg,
    const float* __restrict__ cpartial, const float* __restrict__ b2,
    float* __restrict__ adj)
{
    const int p = blockIdx.x;
    const int t = threadIdx.x;
    if (p >= NTOK) {
        const int d = (p - NTOK) * 256 + t;
        float c[E_NUM];
        float tot = 0.f;
#pragma unroll
        for (int e = 0; e < E_NUM; e++) {
            c[e] = cpartial[(size_t)e * D_DIM + d] + b2[(size_t)e * D_DIM + d];
            tot += c[e];
        }
#pragma unroll
        for (int e = 0; e < E_NUM; e++) adj[(size_t)e * D_DIM + d] = tot - c[e];
        return;
    }
    int e = 0;
    while (e < E_NUM - 1 && p >= off[e] + cnt[e]) e++;
    const int token = list[e * NTOK + (p - off[e])];
    const float* src = x + (size_t)token * D_DIM;
    bf16* dst = Xg + (size_t)p * D_DIM;
    float4 v = *(const float4*)(src + t * 4);
    bf16x4 o;
    o[0] = (bf16)v.x; o[1] = (bf16)v.y; o[2] = (bf16)v.z; o[3] = (bf16)v.w;
    *(bf16x4*)(dst + t * 4) = o;
}

// ---------------- grouped GEMM 1 (m97 structure, blocked-W1t B reads) ----------------
__global__ __launch_bounds__(256) void gemm1_kernel(
    const bf16* __restrict__ Xg, const bf16* __restrict__ W1t,
    const float* __restrict__ b1, const int* __restrict__ cnt,
    const int* __restrict__ off, const int* __restrict__ tile_e,
    const int* __restrict__ tile_row, const int* __restrict__ tile_n,
    bf16* __restrict__ Hb)
{
    const int orig = blockIdx.x;
    const int q = (MAXT * NBY1) >> 3;           // 2304/8 = 288
    const int fid = (orig & 7) * q + (orig >> 3);
    const int tx = fid % MAXT;                  // row-tile inner: B-panel shared on XCD
    const int by = fid / MAXT;
    if (tx >= tile_n[0]) return;
    const int e  = tile_e[tx];
    const int m0 = tile_row[tx];
    const int ne = cnt[e];
    const int oe = off[e];

    __shared__ bf16 As[BM * BK];
    __shared__ bf16 Bs[BN * BK];

    const int t = threadIdx.x;
    const int w = t >> 6, lane = t & 63;
    const int wr = w >> 1, wc = w & 1;
    const int lrow = lane & 15, kq = (lane >> 4) * 8;

    const int lr = lane >> 2;        // 0..15 row within 16-row staging chunk
    const int lc = (lane & 3) * 8;   // elem col within BK
    const bf16* Ast = Xg + ((size_t)(oe + m0 + w * 32 + lr)) * D_DIM + lc;
    bf16* Alds = As + (w * 32) * BK;
    bf16* Blds = Bs + (w * 32) * BK;

    // blocked B: row n = by*128 + w*32 + lr (+16); tile (n>>6, kt>>1),
    // inner (n&63)*64 + (kt&1)*32 + lc. 16 k-tiles per n-tile row (D/64).
    const int r0 = w * 32 + lr, r1 = r0 + 16;
    const bf16* Bb0 = W1t + (size_t)e * D_DIM * H_DIM
                    + ((size_t)(by * 2 + (r0 >> 6)) * (D_DIM / 64)) * 4096
                    + (r0 & 63) * 64 + lc;
    const bf16* Bb1 = W1t + (size_t)e * D_DIM * H_DIM
                    + ((size_t)(by * 2 + (r1 >> 6)) * (D_DIM / 64)) * 4096
                    + (r1 & 63) * 64 + lc;

    f32x4 acc[4][4];
#pragma unroll
    for (int m = 0; m < 4; m++)
#pragma unroll
        for (int n = 0; n < 4; n++) acc[m][n] = (f32x4){0.f, 0.f, 0.f, 0.f};

    for (int kt = 0; kt < D_DIM / BK; kt++) {
        const int kc = kt * BK;
        const int boff = (kt >> 1) * 4096 + (kt & 1) * 32;
        GLOAD16(Ast + kc,              Alds);
        GLOAD16(Ast + 16 * D_DIM + kc, Alds + 16 * BK);
        GLOAD16(Bb0 + boff,            Blds);
        GLOAD16(Bb1 + boff,            Blds + 16 * BK);
        __syncthreads();

        bf16x8 af[4], bfr[4];
#pragma unroll
        for (int m = 0; m < 4; m++)
            af[m] = *(const bf16x8*)&As[(wr * 64 + m * 16 + lrow) * BK + kq];
#pragma unroll
        for (int n = 0; n < 4; n++)
            bfr[n] = *(const bf16x8*)&Bs[(wc * 64 + n * 16 + lrow) * BK + kq];
#pragma unroll
        for (int m = 0; m < 4; m++)
#pragma unroll
            for (int n = 0; n < 4; n++)
                acc[m][n] = __builtin_amdgcn_mfma_f32_16x16x32_bf16(af[m], bfr[n], acc[m][n], 0, 0, 0);
        __syncthreads();
    }

#pragma unroll
    for (int m = 0; m < 4; m++) {
        const int rb0 = m0 + wr * 64 + m * 16 + ((lane >> 4) << 2);
#pragma unroll
        for (int n = 0; n < 4; n++) {
            const int gcol = by * BN + wc * 64 + n * 16 + (lane & 15);
            const float bias = b1[(size_t)e * H_DIM + gcol];
#pragma unroll
            for (int r = 0; r < 4; r++) {
                const int grow = rb0 + r;
                if (grow < ne) {
                    float v = acc[m][n][r] + bias;
                    Hb[((size_t)(oe + grow)) * H_DIM + gcol] = (bf16)fmaxf(v, 0.f);
                }
            }
        }
    }
}

// ---------------- grouped GEMM 2 (m97 structure, blocked-W2t B reads) ----------------
__global__ __launch_bounds__(256) void gemm2_kernel(
    const bf16* __restrict__ Hb, const bf16* __restrict__ W2t,
    const float* __restrict__ b2, const float* __restrict__ adj,
    const int* __restrict__ cnt, const int* __restrict__ off,
    const int* __restrict__ tile_e, const int* __restrict__ tile_row,
    const int* __restrict__ tile_n, const int* __restrict__ list,
    float* __restrict__ out)
{
    const int orig = blockIdx.x;
    const int q = (MAXT * NBY2) >> 3;           // 576/8 = 72
    const int fid = (orig & 7) * q + (orig >> 3);
    const int tx = fid % MAXT;
    const int by = fid / MAXT;
    if (tx >= tile_n[0]) return;
    const int e  = tile_e[tx];
    const int m0 = tile_row[tx];
    const int ne = cnt[e];
    const int oe = off[e];

    __shared__ bf16 As[BM * BK];
    __shared__ bf16 Bs[BN * BK];

    const int t = threadIdx.x;
    const int w = t >> 6, lane = t & 63;
    const int wr = w >> 1, wc = w & 1;
    const int lrow = lane & 15, kq = (lane >> 4) * 8;

    const int lr = lane >> 2;
    const int lc = (lane & 3) * 8;
    const bf16* Ast = Hb + ((size_t)(oe + m0 + w * 32 + lr)) * H_DIM + lc;
    bf16* Alds = As + (w * 32) * BK;
    bf16* Blds = Bs + (w * 32) * BK;

    // blocked B: 64 k-tiles per n-tile row (H/64)
    const int r0 = w * 32 + lr, r1 = r0 + 16;
    const bf16* Bb0 = W2t + (size_t)e * D_DIM * H_DIM
                    + ((size_t)(by * 2 + (r0 >> 6)) * (H_DIM / 64)) * 4096
                    + (r0 & 63) * 64 + lc;
    const bf16* Bb1 = W2t + (size_t)e * D_DIM * H_DIM
                    + ((size_t)(by * 2 + (r1 >> 6)) * (H_DIM / 64)) * 4096
                    + (r1 & 63) * 64 + lc;

    f32x4 acc[4][4];
#pragma unroll
    for (int m = 0; m < 4; m++)
#pragma unroll
        for (int n = 0; n < 4; n++) acc[m][n] = (f32x4){0.f, 0.f, 0.f, 0.f};

    for (int kt = 0; kt < H_DIM / BK; kt++) {
        const int kc = kt * BK;
        const int boff = (kt >> 1) * 4096 + (kt & 1) * 32;
        GLOAD16(Ast + kc,              Alds);
        GLOAD16(Ast + 16 * H_DIM + kc, Alds + 16 * BK);
        GLOAD16(Bb0 + boff,            Blds);
        GLOAD16(Bb1 + boff,            Blds + 16 * BK);
        __syncthreads();

        bf16x8 af[4], bfr[4];
#pragma unroll
        for (int m = 0; m < 4; m++)
            af[m] = *(const bf16x8*)&As[(wr * 64 + m * 16 + lrow) * BK + kq];
#pragma unroll
        for (int n = 0; n < 4; n++)
            bfr[n] = *(const bf16x8*)&Bs[(wc * 64 + n * 16 + lrow) * BK + kq];
#pragma unroll
        for (int m = 0; m < 4; m++)
#pragma unroll
            for (int n = 0; n < 4; n++)
                acc[m][n] = __builtin_amdgcn_mfma_f32_16x16x32_bf16(af[m], bfr[n], acc[m][n], 0, 0, 0);
        __syncthreads();
    }

#pragma unroll
    for (int m = 0; m < 4; m++) {
        const int rb0 = m0 + wr * 64 + m * 16 + ((lane >> 4) << 2);
#pragma unroll
        for (int n = 0; n < 4; n++) {
            const int gcol = by * BN + wc * 64 + n * 16 + (lane & 15);
            const float badj = b2[(size_t)e * D_DIM + gcol] + adj[(size_t)e * D_DIM + gcol];
#pragma unroll
            for (int r = 0; r < 4; r++) {
                const int grow = rb0 + r;
                if (grow < ne) {
                    const int tok = list[e * NTOK + grow];
                    out[(size_t)tok * D_DIM + gcol] = acc[m][n][r] + badj;
                }
            }
        }
    }
}

extern "C" void kernel_launch(void* const* d_in, const int* in_sizes, int n_in,
                              void* d_out, int out_size, void* d_ws, size_t ws_size,
                              hipStream_t stream)
{
    (void)in_sizes; (void)n_in; (void)out_size; (void)ws_size;
    const float* x  = (const float*)d_in[0];
    const float* Wg = (const float*)d_in[1];
    const float* bg = (const float*)d_in[2];
    const float* W1 = (const float*)d_in[3];
    const float* b1 = (const float*)d_in[4];
    const float* W2 = (const float*)d_in[5];
    const float* b2 = (const float*)d_in[6];

    float* out_comb  = (float*)d_out;
    float* out_probs = out_comb + (size_t)NTOK * D_DIM;
    float* out_idx   = out_probs + (size_t)NTOK * E_NUM;

    // ws layout: GEMM A-staging can overread up to 127 rows past the end of
    // Xg (254 KB) and Hb (1 MB) — Xg is followed by cpartial+adj+lists
    // (>1.3 MB) and Hb by Xg (16 MB), so all overshoot stays inside d_ws
    // (values unused: rows >= ne are never written out). B reads are exact.
    char* ws = (char*)d_ws;
    size_t o = 0;
    bf16* W1t = (bf16*)(ws + o); o += (size_t)E_NUM * H_DIM * D_DIM * 2;  // 64MB (blocked)
    bf16* W2t = (bf16*)(ws + o); o += (size_t)E_NUM * H_DIM * D_DIM * 2;  // 64MB (blocked)
    bf16* Hb  = (bf16*)(ws + o); o += (size_t)NTOK * H_DIM * 2;           // 64MB
    bf16* Xg  = (bf16*)(ws + o); o += (size_t)NTOK * D_DIM * 2;           // 16MB
    float* cpartial = (float*)(ws + o); o += (size_t)E_NUM * D_DIM * 4;   // 32KB
    float* adj      = (float*)(ws + o); o += (size_t)E_NUM * D_DIM * 4;   // 32KB
    int* cnt  = (int*)(ws + o); o += 256;
    int* off  = (int*)(ws + o); o += 256;
    int* tile_e   = (int*)(ws + o); o += 512;
    int* tile_row = (int*)(ws + o); o += 512;
    int* tile_n   = (int*)(ws + o); o += 256;
    int* list = (int*)(ws + o); o += (size_t)E_NUM * NTOK * 4;            // 256KB

    zero_kernel<<<(E_NUM * D_DIM + 255) / 256, 256, 0, stream>>>(cnt, cpartial);
    fused_aux_kernel<<<NAUX, 256, 0, stream>>>(W2, W1, b1, x, Wg, bg,
                                               W2t, W1t, cpartial,
                                               out_probs, out_idx, cnt, list);
    offsets_kernel<<<1, 64, 0, stream>>>(cnt, off, tile_e, tile_row, tile_n);
    gather_kernel<<<NTOK + D_DIM / 256, 256, 0, stream>>>(x, off, cnt, list, Xg,
                                                          cpartial, b2, adj);
    gemm1_kernel<<<MAXT * NBY1, 256, 0, stream>>>(Xg, W1t, b1, cnt, off, tile_e, tile_row, tile_n, Hb);
    gemm2_kernel<<<MAXT * NBY2, 256, 0, stream>>>(Hb, W2t, b2, adj, cnt, off, tile_e, tile_row, tile_n, list, out_comb);
}

// Round 21
// 416.842 us; speedup vs baseline: 1.0709x; 1.0709x over previous
//
#include <hip/hip_runtime.h>
#include <hip/hip_bf16.h>
#include <cstdint>

#define D_DIM 1024
#define H_DIM 4096
#define E_NUM 8
#define NTOK  8192

#define BM 128
#define BN 128
#define BK 32

#define MAXT 72             // worst-case 128-row tiles: sum ceil(ne/128) <= 71
#define NBY1 (H_DIM / BN)   // 32
#define NBY2 (D_DIM / BN)   // 8

typedef __bf16 bf16;
typedef __bf16 bf16x8 __attribute__((ext_vector_type(8)));
typedef __bf16 bf16x4 __attribute__((ext_vector_type(4)));
typedef float  f32x4  __attribute__((ext_vector_type(4)));

// global_load_lds: per-lane global src, wave-uniform LDS base + lane*16B dest
#define GLOAD16(g, l)                                                          \
    __builtin_amdgcn_global_load_lds(                                          \
        (const __attribute__((address_space(1))) void*)(g),                    \
        (__attribute__((address_space(3))) void*)(l), 16, 0, 0)

// Blocked weight layout: Wt stored as [ntile][ktile][64][64] bf16 tiles
// (8KB contiguous per tile).

// zero cnt + cpartial
__global__ __launch_bounds__(256) void zero_kernel(int* cnt, float* cpartial)
{
    const int i = blockIdx.x * 256 + threadIdx.x;
    if (i < E_NUM * D_DIM) cpartial[i] = 0.f;
    if (i < E_NUM) cnt[i] = 0;
}

// ---------------- fused aux: W2-transpose(+cpart) | W1-transpose | gate ----------------
//   blocks [0, 8192)      : W2 [H][D] -> W2t blocked, + cpartial
//   blocks [8192, 16384)  : W1 [D][H] -> W1t blocked
//   blocks [16384, 18432) : gating (4 tokens/block, one wave each)
__global__ __launch_bounds__(256) void fused_aux_kernel(
    const float* __restrict__ W2, const float* __restrict__ W1,
    const float* __restrict__ b1,
    const float* __restrict__ x, const float* __restrict__ Wg,
    const float* __restrict__ bg,
    bf16* __restrict__ W2t, bf16* __restrict__ W1t,
    float* __restrict__ cpartial,
    float* __restrict__ out_probs, float* __restrict__ out_idx,
    int* __restrict__ cnt, int* __restrict__ list)
{
    __shared__ float T[64][65];
    const int b = blockIdx.x;
    const int t = threadIdx.x;

    if (b < 8192) {
        // W2 transpose tile: (kx = h-tile 0..63, ny = d-tile 0..15, e)
        const int kx = b & 63, ny = (b >> 6) & 15, e = b >> 10;
        const int k0 = kx * 64, n0 = ny * 64;
        const float* src = W2 + (size_t)e * H_DIM * D_DIM;
        {
            const int ty = t >> 4, tx = (t & 15) * 4;
#pragma unroll
            for (int i = 0; i < 4; i++) {
                f32x4 v = __builtin_nontemporal_load(
                    (const f32x4*)(src + (size_t)(k0 + ty + 16 * i) * D_DIM + n0 + tx));
                T[ty + 16 * i][tx + 0] = v[0]; T[ty + 16 * i][tx + 1] = v[1];
                T[ty + 16 * i][tx + 2] = v[2]; T[ty + 16 * i][tx + 3] = v[3];
            }
        }
        __syncthreads();
        {
            // blocked store: tile (ny, kx) is one contiguous 8KB region
            bf16* dtile = W2t + (size_t)e * H_DIM * D_DIM
                        + ((size_t)ny * (H_DIM / 64) + kx) * 4096;
            const int n = t >> 2, kk = (t & 3) * 16;
            bf16 tmp[16];
#pragma unroll
            for (int j = 0; j < 16; j++) tmp[j] = (bf16)T[kk + j][n];
            *(bf16x8*)(dtile + n * 64 + kk)     = *(bf16x8*)&tmp[0];
            *(bf16x8*)(dtile + n * 64 + kk + 8) = *(bf16x8*)&tmp[8];
        }
        // fused cpart: c[e][d] partial over this h-tile (saves a 128MB W2 re-read)
        if (t < 64) {
            float s = 0.f;
#pragma unroll 8
            for (int h = 0; h < 64; h++)
                s += fmaxf(b1[(size_t)e * H_DIM + k0 + h], 0.f) * T[h][t];
            atomicAdd(&cpartial[(size_t)e * D_DIM + n0 + t], s);
        }
    } else if (b < 16384) {
        // W1 transpose tile: (kx = d-tile 0..15, ny = h-tile 0..63, e)
        const int i2 = b - 8192;
        const int kx = i2 & 15, ny = (i2 >> 4) & 63, e = i2 >> 10;
        const int k0 = kx * 64, n0 = ny * 64;
        const float* src = W1 + (size_t)e * D_DIM * H_DIM;
        {
            const int ty = t >> 4, tx = (t & 15) * 4;
#pragma unroll
            for (int i = 0; i < 4; i++) {
                f32x4 v = __builtin_nontemporal_load(
                    (const f32x4*)(src + (size_t)(k0 + ty + 16 * i) * H_DIM + n0 + tx));
                T[ty + 16 * i][tx + 0] = v[0]; T[ty + 16 * i][tx + 1] = v[1];
                T[ty + 16 * i][tx + 2] = v[2]; T[ty + 16 * i][tx + 3] = v[3];
            }
        }
        __syncthreads();
        {
            bf16* dtile = W1t + (size_t)e * D_DIM * H_DIM
                        + ((size_t)ny * (D_DIM / 64) + kx) * 4096;
            const int n = t >> 2, kk = (t & 3) * 16;
            bf16 tmp[16];
#pragma unroll
            for (int j = 0; j < 16; j++) tmp[j] = (bf16)T[kk + j][n];
            *(bf16x8*)(dtile + n * 64 + kk)     = *(bf16x8*)&tmp[0];
            *(bf16x8*)(dtile + n * 64 + kk + 8) = *(bf16x8*)&tmp[8];
        }
    } else {
        // gating: 4 tokens/block, one wave each
        const int tok = (b - 16384) * 4 + (t >> 6);
        const int l = t & 63;
        double part[E_NUM];
#pragma unroll
        for (int e = 0; e < E_NUM; e++) part[e] = 0.0;
        const float* xr = x + (size_t)tok * D_DIM;
#pragma unroll
        for (int i = 0; i < D_DIM / 64; i++) {
            const int d = l + i * 64;
            const float xv = xr[d];
            const float* wr = Wg + (size_t)d * E_NUM;
            float4 w0 = *(const float4*)(wr);
            float4 w1 = *(const float4*)(wr + 4);
            part[0] += (double)xv * (double)w0.x;
            part[1] += (double)xv * (double)w0.y;
            part[2] += (double)xv * (double)w0.z;
            part[3] += (double)xv * (double)w0.w;
            part[4] += (double)xv * (double)w1.x;
            part[5] += (double)xv * (double)w1.y;
            part[6] += (double)xv * (double)w1.z;
            part[7] += (double)xv * (double)w1.w;
        }
#pragma unroll
        for (int e = 0; e < E_NUM; e++) {
            double v = part[e];
            for (int s = 32; s > 0; s >>= 1) v += __shfl_xor(v, s, 64);
            part[e] = v;
        }
        if (l == 0) {
            float logits[E_NUM], probs[E_NUM];
            float m = -3.0e38f;
#pragma unroll
            for (int e = 0; e < E_NUM; e++) {
                logits[e] = (float)(part[e] + (double)bg[e]);
                m = fmaxf(m, logits[e]);
            }
            float s = 0.f;
#pragma unroll
            for (int e = 0; e < E_NUM; e++) { probs[e] = expf(logits[e] - m); s += probs[e]; }
            const float inv = 1.f / s;
            int best = 0; float bp = -1.f;
#pragma unroll
            for (int e = 0; e < E_NUM; e++) {
                probs[e] *= inv;
                if (probs[e] > bp) { bp = probs[e]; best = e; }
            }
#pragma unroll
            for (int e = 0; e < E_NUM; e++) out_probs[(size_t)tok * E_NUM + e] = probs[e];
            out_idx[tok] = (float)best;
            const int pos = atomicAdd(&cnt[best], 1);
            list[best * NTOK + pos] = tok;
        }
    }
}

// prefix offsets + compact row-tile table (expert, local row0 of each 128-row tile)
__global__ void offsets_kernel(const int* __restrict__ cnt, int* __restrict__ off,
                               int* __restrict__ tile_e, int* __restrict__ tile_row,
                               int* __restrict__ tile_n)
{
    if (threadIdx.x == 0) {
        int a = 0, n = 0;
        for (int e = 0; e < E_NUM; e++) {
            off[e] = a; a += cnt[e];
            for (int rr = 0; rr < cnt[e]; rr += BM) {
                tile_e[n] = e; tile_row[n] = rr; n++;
            }
        }
        tile_n[0] = n;
    }
}

// gather routed x rows into bf16, contiguous per expert.
// Blocks >= NTOK run cfinal (adj from cpartial) — independent work fused.
__global__ __launch_bounds__(256) void gather_kernel(
    const float* __restrict__ x, const int* __restrict__ off,
    const int* __restrict__ cnt, const int* __restrict__ list,
    bf16* __restrict__ Xg,
    const float* __restrict__ cpartial, const float* __restrict__ b2,
    float* __restrict__ adj)
{
    const int p = blockIdx.x;
    const int t = threadIdx.x;
    if (p >= NTOK) {
        const int d = (p - NTOK) * 256 + t;
        float c[E_NUM];
        float tot = 0.f;
#pragma unroll
        for (int e = 0; e < E_NUM; e++) {
            c[e] = cpartial[(size_t)e * D_DIM + d] + b2[(size_t)e * D_DIM + d];
            tot += c[e];
        }
#pragma unroll
        for (int e = 0; e < E_NUM; e++) adj[(size_t)e * D_DIM + d] = tot - c[e];
        return;
    }
    int e = 0;
    while (e < E_NUM - 1 && p >= off[e] + cnt[e]) e++;
    const int token = list[e * NTOK + (p - off[e])];
    const float* src = x + (size_t)token * D_DIM;
    bf16* dst = Xg + (size_t)p * D_DIM;
    float4 v = *(const float4*)(src + t * 4);
    bf16x4 o;
    o[0] = (bf16)v.x; o[1] = (bf16)v.y; o[2] = (bf16)v.z; o[3] = (bf16)v.w;
    *(bf16x4*)(dst + t * 4) = o;
}

// ---------------- grouped GEMM 1 (m97 structure, blocked-W1t B reads) ----------------
__global__ __launch_bounds__(256) void gemm1_kernel(
    const bf16* __restrict__ Xg, const bf16* __restrict__ W1t,
    const float* __restrict__ b1, const int* __restrict__ cnt,
    const int* __restrict__ off, const int* __restrict__ tile_e,
    const int* __restrict__ tile_row, const int* __restrict__ tile_n,
    bf16* __restrict__ Hb)
{
    const int orig = blockIdx.x;
    const int q = (MAXT * NBY1) >> 3;           // 2304/8 = 288
    const int fid = (orig & 7) * q + (orig >> 3);
    const int tx = fid % MAXT;                  // row-tile inner: B-panel shared on XCD
    const int by = fid / MAXT;
    if (tx >= tile_n[0]) return;
    const int e  = tile_e[tx];
    const int m0 = tile_row[tx];
    const int ne = cnt[e];
    const int oe = off[e];

    __shared__ bf16 As[BM * BK];
    __shared__ bf16 Bs[BN * BK];

    const int t = threadIdx.x;
    const int w = t >> 6, lane = t & 63;
    const int wr = w >> 1, wc = w & 1;
    const int lrow = lane & 15, kq = (lane >> 4) * 8;

    const int lr = lane >> 2;        // 0..15 row within 16-row staging chunk
    const int lc = (lane & 3) * 8;   // elem col within BK
    const bf16* Ast = Xg + ((size_t)(oe + m0 + w * 32 + lr)) * D_DIM + lc;
    bf16* Alds = As + (w * 32) * BK;
    bf16* Blds = Bs + (w * 32) * BK;

    // blocked B: row n = by*128 + w*32 + lr (+16); tile (n>>6, kt>>1),
    // inner (n&63)*64 + (kt&1)*32 + lc. 16 k-tiles per n-tile row (D/64).
    const int r0 = w * 32 + lr, r1 = r0 + 16;
    const bf16* Bb0 = W1t + (size_t)e * D_DIM * H_DIM
                    + ((size_t)(by * 2 + (r0 >> 6)) * (D_DIM / 64)) * 4096
                    + (r0 & 63) * 64 + lc;
    const bf16* Bb1 = W1t + (size_t)e * D_DIM * H_DIM
                    + ((size_t)(by * 2 + (r1 >> 6)) * (D_DIM / 64)) * 4096
                    + (r1 & 63) * 64 + lc;

    f32x4 acc[4][4];
#pragma unroll
    for (int m = 0; m < 4; m++)
#pragma unroll
        for (int n = 0; n < 4; n++) acc[m][n] = (f32x4){0.f, 0.f, 0.f, 0.f};

    for (int kt = 0; kt < D_DIM / BK; kt++) {
        const int kc = kt * BK;
        const int boff = (kt >> 1) * 4096 + (kt & 1) * 32;
        GLOAD16(Ast + kc,              Alds);
        GLOAD16(Ast + 16 * D_DIM + kc, Alds + 16 * BK);
        GLOAD16(Bb0 + boff,            Blds);
        GLOAD16(Bb1 + boff,            Blds + 16 * BK);
        __syncthreads();

        bf16x8 af[4], bfr[4];
#pragma unroll
        for (int m = 0; m < 4; m++)
            af[m] = *(const bf16x8*)&As[(wr * 64 + m * 16 + lrow) * BK + kq];
#pragma unroll
        for (int n = 0; n < 4; n++)
            bfr[n] = *(const bf16x8*)&Bs[(wc * 64 + n * 16 + lrow) * BK + kq];
#pragma unroll
        for (int m = 0; m < 4; m++)
#pragma unroll
            for (int n = 0; n < 4; n++)
                acc[m][n] = __builtin_amdgcn_mfma_f32_16x16x32_bf16(af[m], bfr[n], acc[m][n], 0, 0, 0);
        __syncthreads();
    }

#pragma unroll
    for (int m = 0; m < 4; m++) {
        const int rb0 = m0 + wr * 64 + m * 16 + ((lane >> 4) << 2);
#pragma unroll
        for (int n = 0; n < 4; n++) {
            const int gcol = by * BN + wc * 64 + n * 16 + (lane & 15);
            const float bias = b1[(size_t)e * H_DIM + gcol];
#pragma unroll
            for (int r = 0; r < 4; r++) {
                const int grow = rb0 + r;
                if (grow < ne) {
                    float v = acc[m][n][r] + bias;
                    Hb[((size_t)(oe + grow)) * H_DIM + gcol] = (bf16)fmaxf(v, 0.f);
                }
            }
        }
    }
}

// ---------------- grouped GEMM 2 (m97 structure, blocked-W2t B reads) ----------------
__global__ __launch_bounds__(256) void gemm2_kernel(
    const bf16* __restrict__ Hb, const bf16* __restrict__ W2t,
    const float* __restrict__ b2, const float* __restrict__ adj,
    const int* __restrict__ cnt, const int* __restrict__ off,
    const int* __restrict__ tile_e, const int* __restrict__ tile_row,
    const int* __restrict__ tile_n, const int* __restrict__ list,
    float* __restrict__ out)
{
    const int orig = blockIdx.x;
    const int q = (MAXT * NBY2) >> 3;           // 576/8 = 72
    const int fid = (orig & 7) * q + (orig >> 3);
    const int tx = fid % MAXT;
    const int by = fid / MAXT;
    if (tx >= tile_n[0]) return;
    const int e  = tile_e[tx];
    const int m0 = tile_row[tx];
    const int ne = cnt[e];
    const int oe = off[e];

    __shared__ bf16 As[BM * BK];
    __shared__ bf16 Bs[BN * BK];

    const int t = threadIdx.x;
    const int w = t >> 6, lane = t & 63;
    const int wr = w >> 1, wc = w & 1;
    const int lrow = lane & 15, kq = (lane >> 4) * 8;

    const int lr = lane >> 2;
    const int lc = (lane & 3) * 8;
    const bf16* Ast = Hb + ((size_t)(oe + m0 + w * 32 + lr)) * H_DIM + lc;
    bf16* Alds = As + (w * 32) * BK;
    bf16* Blds = Bs + (w * 32) * BK;

    // blocked B: 64 k-tiles per n-tile row (H/64)
    const int r0 = w * 32 + lr, r1 = r0 + 16;
    const bf16* Bb0 = W2t + (size_t)e * D_DIM * H_DIM
                    + ((size_t)(by * 2 + (r0 >> 6)) * (H_DIM / 64)) * 4096
                    + (r0 & 63) * 64 + lc;
    const bf16* Bb1 = W2t + (size_t)e * D_DIM * H_DIM
                    + ((size_t)(by * 2 + (r1 >> 6)) * (H_DIM / 64)) * 4096
                    + (r1 & 63) * 64 + lc;

    f32x4 acc[4][4];
#pragma unroll
    for (int m = 0; m < 4; m++)
#pragma unroll
        for (int n = 0; n < 4; n++) acc[m][n] = (f32x4){0.f, 0.f, 0.f, 0.f};

    for (int kt = 0; kt < H_DIM / BK; kt++) {
        const int kc = kt * BK;
        const int boff = (kt >> 1) * 4096 + (kt & 1) * 32;
        GLOAD16(Ast + kc,              Alds);
        GLOAD16(Ast + 16 * H_DIM + kc, Alds + 16 * BK);
        GLOAD16(Bb0 + boff,            Blds);
        GLOAD16(Bb1 + boff,            Blds + 16 * BK);
        __syncthreads();

        bf16x8 af[4], bfr[4];
#pragma unroll
        for (int m = 0; m < 4; m++)
            af[m] = *(const bf16x8*)&As[(wr * 64 + m * 16 + lrow) * BK + kq];
#pragma unroll
        for (int n = 0; n < 4; n++)
            bfr[n] = *(const bf16x8*)&Bs[(wc * 64 + n * 16 + lrow) * BK + kq];
#pragma unroll
        for (int m = 0; m < 4; m++)
#pragma unroll
            for (int n = 0; n < 4; n++)
                acc[m][n] = __builtin_amdgcn_mfma_f32_16x16x32_bf16(af[m], bfr[n], acc[m][n], 0, 0, 0);
        __syncthreads();
    }

#pragma unroll
    for (int m = 0; m < 4; m++) {
        const int rb0 = m0 + wr * 64 + m * 16 + ((lane >> 4) << 2);
#pragma unroll
        for (int n = 0; n < 4; n++) {
            const int gcol = by * BN + wc * 64 + n * 16 + (lane & 15);
            const float badj = b2[(size_t)e * D_DIM + gcol] + adj[(size_t)e * D_DIM + gcol];
#pragma unroll
            for (int r = 0; r < 4; r++) {
                const int grow = rb0 + r;
                if (grow < ne) {
                    const int tok = list[e * NTOK + grow];
                    out[(size_t)tok * D_DIM + gcol] = acc[m][n][r] + badj;
                }
            }
        }
    }
}

extern "C" void kernel_launch(void* const* d_in, const int* in_sizes, int n_in,
                              void* d_out, int out_size, void* d_ws, size_t ws_size,
                              hipStream_t stream)
{
    (void)in_sizes; (void)n_in; (void)out_size; (void)ws_size;
    const float* x  = (const float*)d_in[0];
    const float* Wg = (const float*)d_in[1];
    const float* bg = (const float*)d_in[2];
    const float* W1 = (const float*)d_in[3];
    const float* b1 = (const float*)d_in[4];
    const float* W2 = (const float*)d_in[5];
    const float* b2 = (const float*)d_in[6];

    float* out_comb  = (float*)d_out;
    float* out_probs = out_comb + (size_t)NTOK * D_DIM;
    float* out_idx   = out_probs + (size_t)NTOK * E_NUM;

    // ws layout: GEMM A-staging can overread up to 127 rows past the end of
    // Xg (254 KB) and Hb (1 MB) — Xg is followed by cpartial+adj+lists
    // (>1.3 MB) and Hb by Xg (16 MB), so all overshoot stays inside d_ws
    // (values unused: rows >= ne are never written out). B reads are exact.
    char* ws = (char*)d_ws;
    size_t o = 0;
    bf16* W1t = (bf16*)(ws + o); o += (size_t)E_NUM * H_DIM * D_DIM * 2;  // 64MB (blocked)
    bf16* W2t = (bf16*)(ws + o); o += (size_t)E_NUM * H_DIM * D_DIM * 2;  // 64MB (blocked)
    bf16* Hb  = (bf16*)(ws + o); o += (size_t)NTOK * H_DIM * 2;           // 64MB
    bf16* Xg  = (bf16*)(ws + o); o += (size_t)NTOK * D_DIM * 2;           // 16MB
    float* cpartial = (float*)(ws + o); o += (size_t)E_NUM * D_DIM * 4;   // 32KB
    float* adj      = (float*)(ws + o); o += (size_t)E_NUM * D_DIM * 4;   // 32KB
    int* cnt  = (int*)(ws + o); o += 256;
    int* off  = (int*)(ws + o); o += 256;
    int* tile_e   = (int*)(ws + o); o += 512;
    int* tile_row = (int*)(ws + o); o += 512;
    int* tile_n   = (int*)(ws + o); o += 256;
    int* list = (int*)(ws + o); o += (size_t)E_NUM * NTOK * 4;            // 256KB

    zero_kernel<<<(E_NUM * D_DIM + 255) / 256, 256, 0, stream>>>(cnt, cpartial);
    fused_aux_kernel<<<18432, 256, 0, stream>>>(W2, W1, b1, x, Wg, bg,
                                                W2t, W1t, cpartial,
                                                out_probs, out_idx, cnt, list);
    offsets_kernel<<<1, 64, 0, stream>>>(cnt, off, tile_e, tile_row, tile_n);
    gather_kernel<<<NTOK + D_DIM / 256, 256, 0, stream>>>(x, off, cnt, list, Xg,
                                                          cpartial, b2, adj);
    gemm1_kernel<<<MAXT * NBY1, 256, 0, stream>>>(Xg, W1t, b1, cnt, off, tile_e, tile_row, tile_n, Hb);
    gemm2_kernel<<<MAXT * NBY2, 256, 0, stream>>>(Hb, W2t, b2, adj, cnt, off, tile_e, tile_row, tile_n, list, out_comb);
}